// Round 1
// baseline (2141.671 us; speedup 1.0000x reference)
//
#include <hip/hip_runtime.h>
#include <math.h>

// Problem constants
#define M_TOK 32768   // B*S = 8*4096
#define D_IN  1024
#define F_HID 2048
#define E_EXP 64
// Tiling
#define BT 64         // tokens per block
#define FC 128        // F-chunk
#define DC 32         // D-chunk

#define O_ORI 0
#define O_RTR (M_TOK * E_EXP)          // 2097152
#define O_IDX (2 * M_TOK * E_EXP)      // 4194304

__launch_bounds__(256, 2)
__global__ void router_fused(const float* __restrict__ x,
                             const float* __restrict__ W1,
                             const float* __restrict__ b1,
                             const float* __restrict__ W2,
                             const float* __restrict__ b2,
                             float* __restrict__ out)
{
    __shared__ float xs[BT][DC];    // 8 KB
    __shared__ float w1s[DC][FC];   // 16 KB
    __shared__ float hs[BT][FC];    // 32 KB

    const int tid  = threadIdx.x;
    const size_t tok0 = (size_t)blockIdx.x * BT;

    // GEMM1 tile mapping: 8 row-groups x 32 col-groups
    const int g8 = (tid >> 5) * 8;        // base row (8 rows per thread)
    const int c4 = (tid & 31) * 4;        // base col (4 cols per thread)

    // GEMM2 / epilogue mapping
    const int wid = tid >> 6;             // wave id, owns rows wid*16..+15
    const int e   = tid & 63;             // expert lane

    float lacc[16];
#pragma unroll
    for (int i = 0; i < 16; ++i) lacc[i] = 0.f;

    for (int fc = 0; fc < F_HID; fc += FC) {
        float acc[8][4];
#pragma unroll
        for (int i = 0; i < 8; ++i)
#pragma unroll
            for (int j = 0; j < 4; ++j) acc[i][j] = 0.f;

        for (int d0 = 0; d0 < D_IN; d0 += DC) {
            __syncthreads();   // previous readers of xs/w1s (and prev-fc hs readers) done
            // stage x slice: [BT][DC], 2 float4 per thread
            {
                const int r  = tid >> 3;          // 0..31
                const int dd = (tid & 7) * 4;     // 0..28
#pragma unroll
                for (int p = 0; p < 2; ++p) {
                    const int rr = r + p * 32;
                    const float4 v = *(const float4*)&x[(tok0 + rr) * D_IN + d0 + dd];
                    *(float4*)&xs[rr][dd] = v;
                }
            }
            // stage W1 slice: [DC][FC], 4 float4 per thread
            {
                const int f4 = (tid & 31) * 4;    // 0..124
                const int db = tid >> 5;          // 0..7
#pragma unroll
                for (int p = 0; p < 4; ++p) {
                    const int dd = db + p * 8;
                    const float4 v = *(const float4*)&W1[(size_t)(d0 + dd) * F_HID + fc + f4];
                    *(float4*)&w1s[dd][f4] = v;
                }
            }
            __syncthreads();

#pragma unroll 4
            for (int dd = 0; dd < DC; dd += 4) {
                float4 wv[4];
#pragma unroll
                for (int q = 0; q < 4; ++q) wv[q] = *(const float4*)&w1s[dd + q][c4];
#pragma unroll
                for (int i = 0; i < 8; ++i) {
                    const float4 xv = *(const float4*)&xs[g8 + i][dd];
                    const float xq[4] = {xv.x, xv.y, xv.z, xv.w};
#pragma unroll
                    for (int q = 0; q < 4; ++q) {
                        acc[i][0] = fmaf(xq[q], wv[q].x, acc[i][0]);
                        acc[i][1] = fmaf(xq[q], wv[q].y, acc[i][1]);
                        acc[i][2] = fmaf(xq[q], wv[q].z, acc[i][2]);
                        acc[i][3] = fmaf(xq[q], wv[q].w, acc[i][3]);
                    }
                }
            }
        }

        // bias + relu -> hs
        {
            const float4 bv = *(const float4*)&b1[fc + c4];
#pragma unroll
            for (int i = 0; i < 8; ++i) {
                float4 hv;
                hv.x = fmaxf(acc[i][0] + bv.x, 0.f);
                hv.y = fmaxf(acc[i][1] + bv.y, 0.f);
                hv.z = fmaxf(acc[i][2] + bv.z, 0.f);
                hv.w = fmaxf(acc[i][3] + bv.w, 0.f);
                *(float4*)&hs[g8 + i][c4] = hv;
            }
        }
        __syncthreads();

        // GEMM2 partial: logits[r][e] += relu(h)[r][f] * W2[f][e]
        for (int f = 0; f < FC; f += 4) {
            const float w0 = W2[(size_t)(fc + f + 0) * E_EXP + e];
            const float w1v = W2[(size_t)(fc + f + 1) * E_EXP + e];
            const float w2v = W2[(size_t)(fc + f + 2) * E_EXP + e];
            const float w3v = W2[(size_t)(fc + f + 3) * E_EXP + e];
#pragma unroll
            for (int i = 0; i < 16; ++i) {
                const float4 hv = *(const float4*)&hs[wid * 16 + i][f];
                lacc[i] = fmaf(hv.x, w0, lacc[i]);
                lacc[i] = fmaf(hv.y, w1v, lacc[i]);
                lacc[i] = fmaf(hv.z, w2v, lacc[i]);
                lacc[i] = fmaf(hv.w, w3v, lacc[i]);
            }
        }
    }

    // Epilogue: per row, top-2 + softmaxes across the 64-lane wave (lane == expert)
    const float be = b2[e];
#pragma unroll 1
    for (int i = 0; i < 16; ++i) {
        const float l = lacc[i] + be;

        // top-1 (ties -> lower index, matching jax.lax.top_k)
        float v = l; int idx = e;
#pragma unroll
        for (int m = 32; m >= 1; m >>= 1) {
            const float ov = __shfl_xor(v, m, 64);
            const int   oi = __shfl_xor(idx, m, 64);
            if (ov > v || (ov == v && oi < idx)) { v = ov; idx = oi; }
        }
        const float m1 = v; const int i1 = idx;

        // top-2
        v = (e == i1) ? -INFINITY : l; idx = e;
#pragma unroll
        for (int m = 32; m >= 1; m >>= 1) {
            const float ov = __shfl_xor(v, m, 64);
            const int   oi = __shfl_xor(idx, m, 64);
            if (ov > v || (ov == v && oi < idx)) { v = ov; idx = oi; }
        }
        const int i2 = idx;

        // ori softmax with temp 0.01
        const float ex = expf((l - m1) * 100.0f);
        float s = ex;
#pragma unroll
        for (int m = 32; m >= 1; m >>= 1) s += __shfl_xor(s, m, 64);
        const float ori = ex / s;

        // sparse (top-2) softmax; max of kept == m1
        const float q = (e == i1 || e == i2) ? expf(l - m1) : 0.f;
        float s2 = q;
#pragma unroll
        for (int m = 32; m >= 1; m >>= 1) s2 += __shfl_xor(s2, m, 64);
        const float rtr = q / s2;

        const size_t tok = tok0 + (size_t)wid * 16 + i;
        out[O_ORI + tok * E_EXP + e] = ori;
        out[O_RTR + tok * E_EXP + e] = rtr;
        if (e == 0) {
            out[O_IDX + tok * 2 + 0] = (float)i1;
            out[O_IDX + tok * 2 + 1] = (float)i2;
        }
    }
}

extern "C" void kernel_launch(void* const* d_in, const int* in_sizes, int n_in,
                              void* d_out, int out_size, void* d_ws, size_t ws_size,
                              hipStream_t stream) {
    const float* x  = (const float*)d_in[0];
    const float* W1 = (const float*)d_in[1];
    const float* b1 = (const float*)d_in[2];
    const float* W2 = (const float*)d_in[3];
    const float* b2 = (const float*)d_in[4];
    float* out = (float*)d_out;

    dim3 grid(M_TOK / BT);   // 512
    dim3 block(256);
    hipLaunchKernelGGL(router_fused, grid, block, 0, stream, x, W1, b1, W2, b2, out);
}

// Round 2
// 914.420 us; speedup vs baseline: 2.3421x; 2.3421x over previous
//
#include <hip/hip_runtime.h>
#include <math.h>

// Problem constants
#define M_TOK 32768   // B*S
#define D_IN  1024
#define F_HID 2048
#define E_EXP 64
// Tiling
#define BT     64     // tokens per block
#define FCHUNK 128    // F-chunk
#define DCHUNK 32     // D-chunk (= MFMA K)
#define XPITCH 80     // bytes per xs row (32 halves = 64B + 16B pad -> 8 distinct bank-quads)
#define WPITCH 80     // bytes per w1s row
#define HPITCH 132    // floats per hs row (128 + 4 pad -> 2-way max on writes)

#define O_ORI 0
#define O_RTR (M_TOK * E_EXP)
#define O_IDX (2 * M_TOK * E_EXP)

typedef _Float16 half8 __attribute__((ext_vector_type(8)));
typedef float    f32x4 __attribute__((ext_vector_type(4)));

__launch_bounds__(256, 2)
__global__ void router_fused(const float* __restrict__ x,
                             const float* __restrict__ W1,
                             const float* __restrict__ bias1,
                             const float* __restrict__ W2,
                             const float* __restrict__ bias2,
                             float* __restrict__ out)
{
    // LDS: 5120*2 + 10240*2 + 33792 = 64512 B  -> 2 blocks/CU
    __shared__ __align__(16) unsigned char xs_h[BT * XPITCH];
    __shared__ __align__(16) unsigned char xs_l[BT * XPITCH];
    __shared__ __align__(16) unsigned char w1s_h[FCHUNK * WPITCH];
    __shared__ __align__(16) unsigned char w1s_l[FCHUNK * WPITCH];
    __shared__ float hs[BT][HPITCH];

    const int tid  = threadIdx.x;
    const int lane = tid & 63;
    const int wid  = tid >> 6;
    const size_t tok0 = (size_t)blockIdx.x * BT;

    // wave tile: wr = 32-row half, wc = 64-col half of the 64x128 block tile
    const int wr = wid >> 1, wc = wid & 1;

    // staging assignments
    const int sx_r = tid >> 2;            // x: token row 0..63
    const int sx_d = (tid & 3) * 8;       // x: d-offset in halves
    const int sw_f = tid & 127;           // W1: f column 0..127
    const int sw_q = tid >> 7;            // W1: d-quad (16 d's each)

    // GEMM2 / epilogue mapping: lane == expert
    const int e = lane;

    float lacc[16];
#pragma unroll
    for (int i = 0; i < 16; ++i) lacc[i] = 0.f;

    for (int fc = 0; fc < F_HID; fc += FCHUNK) {
        f32x4 acc_hh[2][4], acc_x[2][4];
#pragma unroll
        for (int mt = 0; mt < 2; ++mt)
#pragma unroll
            for (int nt = 0; nt < 4; ++nt) {
                acc_hh[mt][nt] = (f32x4){0.f, 0.f, 0.f, 0.f};
                acc_x[mt][nt]  = (f32x4){0.f, 0.f, 0.f, 0.f};
            }

        for (int d0 = 0; d0 < D_IN; d0 += DCHUNK) {
            __syncthreads();   // previous readers of xs/w1s done
            // ---- stage x[64][32] -> fp16 hi/lo (split: a = hi + lo*2^-12, lo prescaled 4096)
            {
                const float* xp = &x[(tok0 + sx_r) * D_IN + d0 + sx_d];
                const float4 v0 = *(const float4*)xp;
                const float4 v1 = *(const float4*)(xp + 4);
                const float vv[8] = {v0.x, v0.y, v0.z, v0.w, v1.x, v1.y, v1.z, v1.w};
                half8 hh, hl;
#pragma unroll
                for (int j = 0; j < 8; ++j) {
                    const float v = vv[j];
                    const _Float16 h = (_Float16)v;
                    const float r = v - (float)h;
                    hh[j] = h;
                    hl[j] = (_Float16)(r * 4096.f);
                }
                *(half8*)(xs_h + sx_r * XPITCH + sx_d * 2) = hh;
                *(half8*)(xs_l + sx_r * XPITCH + sx_d * 2) = hl;
            }
            // ---- stage W1[32][128] transposed -> w1s[f][d] fp16 hi/lo (K-contiguous)
            {
                const float* wp = &W1[(size_t)(d0 + sw_q * 16) * F_HID + fc + sw_f];
                half8 h0, h1, l0, l1;
#pragma unroll
                for (int j = 0; j < 8; ++j) {
                    const float v = wp[(size_t)j * F_HID];
                    const _Float16 h = (_Float16)v;
                    const float r = v - (float)h;
                    h0[j] = h; l0[j] = (_Float16)(r * 4096.f);
                }
#pragma unroll
                for (int j = 0; j < 8; ++j) {
                    const float v = wp[(size_t)(j + 8) * F_HID];
                    const _Float16 h = (_Float16)v;
                    const float r = v - (float)h;
                    h1[j] = h; l1[j] = (_Float16)(r * 4096.f);
                }
                unsigned char* bh_ = w1s_h + sw_f * WPITCH + sw_q * 32;
                unsigned char* bl_ = w1s_l + sw_f * WPITCH + sw_q * 32;
                *(half8*)(bh_)      = h0;
                *(half8*)(bh_ + 16) = h1;
                *(half8*)(bl_)      = l0;
                *(half8*)(bl_ + 16) = l1;
            }
            __syncthreads();

            // ---- MFMA: 2m x 4n tiles, 3 products each
            const int koff = (lane >> 4) * 16;   // byte offset of this lane's k-group (8 halves)
            half8 ah[2], al[2], bh[4], bl[4];
#pragma unroll
            for (int mt = 0; mt < 2; ++mt) {
                const int row = wr * 32 + mt * 16 + (lane & 15);
                ah[mt] = *(const half8*)(xs_h + row * XPITCH + koff);
                al[mt] = *(const half8*)(xs_l + row * XPITCH + koff);
            }
#pragma unroll
            for (int nt = 0; nt < 4; ++nt) {
                const int f = wc * 64 + nt * 16 + (lane & 15);
                bh[nt] = *(const half8*)(w1s_h + f * WPITCH + koff);
                bl[nt] = *(const half8*)(w1s_l + f * WPITCH + koff);
            }
#pragma unroll
            for (int mt = 0; mt < 2; ++mt)
#pragma unroll
                for (int nt = 0; nt < 4; ++nt) {
                    acc_hh[mt][nt] = __builtin_amdgcn_mfma_f32_16x16x32_f16(ah[mt], bh[nt], acc_hh[mt][nt], 0, 0, 0);
                    acc_x[mt][nt]  = __builtin_amdgcn_mfma_f32_16x16x32_f16(ah[mt], bl[nt], acc_x[mt][nt], 0, 0, 0);
                    acc_x[mt][nt]  = __builtin_amdgcn_mfma_f32_16x16x32_f16(al[mt], bh[nt], acc_x[mt][nt], 0, 0, 0);
                }
        }

        // ---- combine split accumulators + bias + relu -> hs (f32)
#pragma unroll
        for (int mt = 0; mt < 2; ++mt)
#pragma unroll
            for (int nt = 0; nt < 4; ++nt) {
                const int f = wc * 64 + nt * 16 + (lane & 15);
                const float bv = bias1[fc + f];
#pragma unroll
                for (int r = 0; r < 4; ++r) {
                    const int row = wr * 32 + mt * 16 + (lane >> 4) * 4 + r;
                    const float v = acc_hh[mt][nt][r] + acc_x[mt][nt][r] * (1.f / 4096.f) + bv;
                    hs[row][f] = fmaxf(v, 0.f);
                }
            }
        __syncthreads();

        // ---- GEMM2 partial (f32 VALU; hs reads are lane-broadcast)
        for (int f = 0; f < FCHUNK; f += 4) {
            const float w0  = W2[(size_t)(fc + f + 0) * E_EXP + e];
            const float w1v = W2[(size_t)(fc + f + 1) * E_EXP + e];
            const float w2v = W2[(size_t)(fc + f + 2) * E_EXP + e];
            const float w3v = W2[(size_t)(fc + f + 3) * E_EXP + e];
#pragma unroll
            for (int i = 0; i < 16; ++i) {
                const float4 hv = *(const float4*)&hs[wid * 16 + i][f];
                lacc[i] = fmaf(hv.x, w0,  lacc[i]);
                lacc[i] = fmaf(hv.y, w1v, lacc[i]);
                lacc[i] = fmaf(hv.z, w2v, lacc[i]);
                lacc[i] = fmaf(hv.w, w3v, lacc[i]);
            }
        }
    }

    // ---- Epilogue: per row, top-2 + softmaxes across the 64-lane wave (lane == expert)
    const float be = bias2[e];
#pragma unroll 1
    for (int i = 0; i < 16; ++i) {
        const float l = lacc[i] + be;

        // top-1 (ties -> lower index)
        float v = l; int idx = e;
#pragma unroll
        for (int m = 32; m >= 1; m >>= 1) {
            const float ov = __shfl_xor(v, m, 64);
            const int   oi = __shfl_xor(idx, m, 64);
            if (ov > v || (ov == v && oi < idx)) { v = ov; idx = oi; }
        }
        const float m1 = v; const int i1 = idx;

        // top-2
        v = (e == i1) ? -INFINITY : l; idx = e;
#pragma unroll
        for (int m = 32; m >= 1; m >>= 1) {
            const float ov = __shfl_xor(v, m, 64);
            const int   oi = __shfl_xor(idx, m, 64);
            if (ov > v || (ov == v && oi < idx)) { v = ov; idx = oi; }
        }
        const int i2 = idx;

        // ori softmax with temp 0.01
        const float ex = expf((l - m1) * 100.0f);
        float s = ex;
#pragma unroll
        for (int m = 32; m >= 1; m >>= 1) s += __shfl_xor(s, m, 64);
        const float ori = ex / s;

        // sparse (top-2) softmax
        const float q = (e == i1 || e == i2) ? expf(l - m1) : 0.f;
        float s2 = q;
#pragma unroll
        for (int m = 32; m >= 1; m >>= 1) s2 += __shfl_xor(s2, m, 64);
        const float rtr = q / s2;

        const size_t tok = tok0 + (size_t)wid * 16 + i;
        out[O_ORI + tok * E_EXP + e] = ori;
        out[O_RTR + tok * E_EXP + e] = rtr;
        if (e == 0) {
            out[O_IDX + tok * 2 + 0] = (float)i1;
            out[O_IDX + tok * 2 + 1] = (float)i2;
        }
    }
}

extern "C" void kernel_launch(void* const* d_in, const int* in_sizes, int n_in,
                              void* d_out, int out_size, void* d_ws, size_t ws_size,
                              hipStream_t stream) {
    const float* x  = (const float*)d_in[0];
    const float* W1 = (const float*)d_in[1];
    const float* b1 = (const float*)d_in[2];
    const float* W2 = (const float*)d_in[3];
    const float* b2 = (const float*)d_in[4];
    float* out = (float*)d_out;

    dim3 grid(M_TOK / BT);   // 512
    dim3 block(256);
    hipLaunchKernelGGL(router_fused, grid, block, 0, stream, x, W1, b1, W2, b2, out);
}

// Round 3
// 610.078 us; speedup vs baseline: 3.5105x; 1.4989x over previous
//
#include <hip/hip_runtime.h>
#include <math.h>
#include <stdint.h>

// Problem constants
#define M_TOK 32768   // B*S
#define D_IN  1024
#define F_HID 2048
#define E_EXP 64

// Main-kernel tiling: block = 64 tokens x 256 f-chunk, 4 waves, wave-tile 64x64
#define BT  64
#define NB  256
#define KC  32

#define O_ORI 0
#define O_RTR (M_TOK * E_EXP)
#define O_IDX (2 * M_TOK * E_EXP)

typedef _Float16 half8 __attribute__((ext_vector_type(8)));
typedef float    f32x4 __attribute__((ext_vector_type(4)));
typedef unsigned int   uint32;
typedef uint32   u32x4 __attribute__((ext_vector_type(4)));
typedef unsigned short ushort16_t;

// ---- workspace layout (bytes) ----
#define WS_XH  ((size_t)0)
#define WS_XL  (WS_XH  + (size_t)M_TOK * D_IN * 2)
#define WS_W1H (WS_XL  + (size_t)M_TOK * D_IN * 2)
#define WS_W1L (WS_W1H + (size_t)D_IN * F_HID * 2)
#define WS_W2H (WS_W1L + (size_t)D_IN * F_HID * 2)
#define WS_W2L (WS_W2H + (size_t)F_HID * E_EXP * 2)
#define WS_NEED (WS_W2L + (size_t)F_HID * E_EXP * 2)

__device__ __forceinline__ void split1(float v, unsigned short& h, unsigned short& l) {
    _Float16 hh = (_Float16)v;
    float r = (v - (float)hh) * 4096.f;   // prescale so residual stays normal in fp16
    _Float16 ll = (_Float16)r;
    h = __builtin_bit_cast(unsigned short, hh);
    l = __builtin_bit_cast(unsigned short, ll);
}

// ============ prep kernels ============

__global__ void split_x_k(const float* __restrict__ x,
                          unsigned short* __restrict__ xh, unsigned short* __restrict__ xl) {
    size_t i = ((size_t)blockIdx.x * 256 + threadIdx.x) * 4;
    const float4 v = *(const float4*)&x[i];
    ushort4 h, l;
    split1(v.x, h.x, l.x); split1(v.y, h.y, l.y);
    split1(v.z, h.z, l.z); split1(v.w, h.w, l.w);
    *(ushort4*)&xh[i] = h;
    *(ushort4*)&xl[i] = l;
}

__global__ void split_w1t_k(const float* __restrict__ W1,
                            unsigned short* __restrict__ wh, unsigned short* __restrict__ wl) {
    __shared__ float t[32][33];
    const int d0 = blockIdx.x * 32;    // 32 tiles over D
    const int f0 = blockIdx.y * 32;    // 64 tiles over F
    const int r  = threadIdx.x >> 3;
    const int c4 = (threadIdx.x & 7) * 4;
    const float4 v = *(const float4*)&W1[(size_t)(d0 + r) * F_HID + f0 + c4];
    t[r][c4 + 0] = v.x; t[r][c4 + 1] = v.y; t[r][c4 + 2] = v.z; t[r][c4 + 3] = v.w;
    __syncthreads();
    ushort4 h, l;
    split1(t[c4 + 0][r], h.x, l.x);
    split1(t[c4 + 1][r], h.y, l.y);
    split1(t[c4 + 2][r], h.z, l.z);
    split1(t[c4 + 3][r], h.w, l.w);
    *(ushort4*)&wh[(size_t)(f0 + r) * D_IN + d0 + c4] = h;
    *(ushort4*)&wl[(size_t)(f0 + r) * D_IN + d0 + c4] = l;
}

__global__ void split_w2t_k(const float* __restrict__ W2,
                            unsigned short* __restrict__ wh, unsigned short* __restrict__ wl) {
    const int gid = blockIdx.x * 256 + threadIdx.x;    // 32768 threads
    const int e  = gid >> 9;
    const int f4 = (gid & 511) * 4;
    ushort4 h, l;
    split1(W2[(size_t)(f4 + 0) * E_EXP + e], h.x, l.x);
    split1(W2[(size_t)(f4 + 1) * E_EXP + e], h.y, l.y);
    split1(W2[(size_t)(f4 + 2) * E_EXP + e], h.z, l.z);
    split1(W2[(size_t)(f4 + 3) * E_EXP + e], h.w, l.w);
    *(ushort4*)&wh[(size_t)e * F_HID + f4] = h;
    *(ushort4*)&wl[(size_t)e * F_HID + f4] = l;
}

// ============ main fused kernel ============

__device__ __forceinline__ uint32 swz(uint32 o) { return o ^ (((o >> 7) & 7u) << 4); }

#define STAGE16(SRCP, DSTP) \
    __builtin_amdgcn_global_load_lds((const __attribute__((address_space(1))) void*)(SRCP), \
                                     (__attribute__((address_space(3))) void*)(DSTP), 16, 0, 0)

__launch_bounds__(256, 2)
__global__ void router_mfma(const unsigned short* __restrict__ xh, const unsigned short* __restrict__ xl,
                            const unsigned short* __restrict__ w1h, const unsigned short* __restrict__ w1l,
                            const unsigned short* __restrict__ w2h, const unsigned short* __restrict__ w2l,
                            const float* __restrict__ b1, const float* __restrict__ b2,
                            float* __restrict__ out)
{
    // LDS: 4K+4K + 16K+16K + 33792 = 74752 B -> 2 blocks/CU
    __shared__ __align__(16) unsigned char xs_h[BT * 64];
    __shared__ __align__(16) unsigned char xs_l[BT * 64];
    __shared__ __align__(16) unsigned char w1s_h[NB * 64];
    __shared__ __align__(16) unsigned char w1s_l[NB * 64];
    __shared__ __align__(16) unsigned char hsbuf[BT * 132 * 4];   // packed h (u32) / logits (f32)

    const int tid  = threadIdx.x;
    const int lane = tid & 63;
    const int w    = tid >> 6;          // wave 0..3
    const int c15  = lane & 15;
    const int g    = lane >> 4;         // k-quarter
    const size_t tok0 = (size_t)blockIdx.x * BT;

    uint32* hs = (uint32*)hsbuf;        // [64][132] packed (hi | lo<<16)
    float*  ls = (float*)hsbuf;         // [64][68] logits (reused at epilogue)

    f32x4 acc2h[4], acc2x[4];           // GEMM2: 16 tokens x 64 experts per wave
#pragma unroll
    for (int nt = 0; nt < 4; ++nt) {
        acc2h[nt] = (f32x4){0.f, 0.f, 0.f, 0.f};
        acc2x[nt] = (f32x4){0.f, 0.f, 0.f, 0.f};
    }

    const uint32 kqb = (uint32)g * 16u;   // k-group byte offset within 64-B row

    for (int fc = 0; fc < F_HID; fc += NB) {
        f32x4 ahh[4][4], axx[4][4];       // GEMM1 wave-tile 64x64: 4 m x 4 n
#pragma unroll
        for (int mt = 0; mt < 4; ++mt)
#pragma unroll
            for (int nt = 0; nt < 4; ++nt) {
                ahh[mt][nt] = (f32x4){0.f, 0.f, 0.f, 0.f};
                axx[mt][nt] = (f32x4){0.f, 0.f, 0.f, 0.f};
            }

        for (int d0 = 0; d0 < D_IN; d0 += KC) {
            __syncthreads();   // prev readers of xs/w1s (and prev chunk's hs readers) done
            // ---- stage via global_load_lds, swizzled source (10 jobs per wave) ----
            {
                // xs_h / xs_l : 4 chunks each, chunk = w
                uint32 o = (uint32)w * 1024u + (uint32)lane * 16u;
                uint32 s = swz(o);
                uint32 r = s >> 6, hb = (s & 63u) >> 1;
                const unsigned short* sp;
                sp = xh + (tok0 + r) * D_IN + (size_t)(d0 + (int)hb);
                STAGE16(sp, xs_h + (size_t)w * 1024);
                sp = xl + (tok0 + r) * D_IN + (size_t)(d0 + (int)hb);
                STAGE16(sp, xs_l + (size_t)w * 1024);
                // w1s_h / w1s_l : 16 chunks each, chunks q*4+w
#pragma unroll
                for (int q = 0; q < 4; ++q) {
                    const uint32 c_ = (uint32)(q * 4 + w);
                    uint32 o2 = c_ * 1024u + (uint32)lane * 16u;
                    uint32 s2 = swz(o2);
                    uint32 r2 = s2 >> 6, hb2 = (s2 & 63u) >> 1;
                    sp = w1h + ((size_t)(fc + (int)r2)) * D_IN + (size_t)(d0 + (int)hb2);
                    STAGE16(sp, w1s_h + (size_t)c_ * 1024);
                    sp = w1l + ((size_t)(fc + (int)r2)) * D_IN + (size_t)(d0 + (int)hb2);
                    STAGE16(sp, w1s_l + (size_t)c_ * 1024);
                }
            }
            __syncthreads();

            // ---- fragments + MFMA (3-product fp16 split) ----
            half8 ah[4], al[4], bh[4], bl[4];
#pragma unroll
            for (int mt = 0; mt < 4; ++mt) {
                const uint32 off = swz((uint32)(mt * 16 + c15) * 64u + kqb);
                ah[mt] = *(const half8*)(xs_h + off);
                al[mt] = *(const half8*)(xs_l + off);
            }
#pragma unroll
            for (int nt = 0; nt < 4; ++nt) {
                const uint32 row = (uint32)(w * 64 + nt * 16 + c15);
                const uint32 off = swz(row * 64u + kqb);
                bh[nt] = *(const half8*)(w1s_h + off);
                bl[nt] = *(const half8*)(w1s_l + off);
            }
#pragma unroll
            for (int mt = 0; mt < 4; ++mt)
#pragma unroll
                for (int nt = 0; nt < 4; ++nt) {
                    ahh[mt][nt] = __builtin_amdgcn_mfma_f32_16x16x32_f16(ah[mt], bh[nt], ahh[mt][nt], 0, 0, 0);
                    axx[mt][nt] = __builtin_amdgcn_mfma_f32_16x16x32_f16(ah[mt], bl[nt], axx[mt][nt], 0, 0, 0);
                    axx[mt][nt] = __builtin_amdgcn_mfma_f32_16x16x32_f16(al[mt], bh[nt], axx[mt][nt], 0, 0, 0);
                }
        }

        // ---- h = relu(acc + b1), split-pack to LDS; GEMM2 in two 128-f phases ----
        const int fl0 = (w & 1) * 64;   // this wave's f-offset within its phase
#pragma unroll
        for (int phase = 0; phase < 2; ++phase) {
            if ((w >> 1) == phase) {
#pragma unroll
                for (int nt = 0; nt < 4; ++nt) {
                    const float b1v = b1[fc + w * 64 + nt * 16 + c15];
#pragma unroll
                    for (int mt = 0; mt < 4; ++mt) {
#pragma unroll
                        for (int r = 0; r < 4; ++r) {
                            float hv = ahh[mt][nt][r] + axx[mt][nt][r] * (1.f / 4096.f) + b1v;
                            hv = fmaxf(hv, 0.f);
                            _Float16 hhv = (_Float16)hv;
                            float rr = (hv - (float)hhv) * 4096.f;
                            _Float16 hlv = (_Float16)rr;
                            uint32 pk = (uint32)__builtin_bit_cast(unsigned short, hhv)
                                      | ((uint32)__builtin_bit_cast(unsigned short, hlv) << 16);
                            const int t = mt * 16 + g * 4 + r;
                            hs[t * 132 + fl0 + nt * 16 + c15] = pk;
                        }
                    }
                }
            }
            __syncthreads();
            // GEMM2 on this 128-f phase: logits[tok 16/wave][64 e]
            const int tA = w * 16 + c15;
#pragma unroll
            for (int ktl = 0; ktl < 4; ++ktl) {
                const u32x4 q0 = *(const u32x4*)&hs[tA * 132 + ktl * 32 + g * 8];
                const u32x4 q1 = *(const u32x4*)&hs[tA * 132 + ktl * 32 + g * 8 + 4];
                u32x4 hi4, lo4;
                hi4[0] = __builtin_amdgcn_perm(q0[1], q0[0], 0x05040100u);
                hi4[1] = __builtin_amdgcn_perm(q0[3], q0[2], 0x05040100u);
                hi4[2] = __builtin_amdgcn_perm(q1[1], q1[0], 0x05040100u);
                hi4[3] = __builtin_amdgcn_perm(q1[3], q1[2], 0x05040100u);
                lo4[0] = __builtin_amdgcn_perm(q0[1], q0[0], 0x07060302u);
                lo4[1] = __builtin_amdgcn_perm(q0[3], q0[2], 0x07060302u);
                lo4[2] = __builtin_amdgcn_perm(q1[1], q1[0], 0x07060302u);
                lo4[3] = __builtin_amdgcn_perm(q1[3], q1[2], 0x07060302u);
                const half8 a_h = __builtin_bit_cast(half8, hi4);
                const half8 a_l = __builtin_bit_cast(half8, lo4);
                const int fG = fc + (phase * 4 + ktl) * 32 + g * 8;
#pragma unroll
                for (int nt = 0; nt < 4; ++nt) {
                    const int e_ = nt * 16 + c15;
                    const half8 b_h = *(const half8*)&w2h[(size_t)e_ * F_HID + fG];
                    const half8 b_l = *(const half8*)&w2l[(size_t)e_ * F_HID + fG];
                    acc2h[nt] = __builtin_amdgcn_mfma_f32_16x16x32_f16(a_h, b_h, acc2h[nt], 0, 0, 0);
                    acc2x[nt] = __builtin_amdgcn_mfma_f32_16x16x32_f16(a_h, b_l, acc2x[nt], 0, 0, 0);
                    acc2x[nt] = __builtin_amdgcn_mfma_f32_16x16x32_f16(a_l, b_h, acc2x[nt], 0, 0, 0);
                }
            }
            __syncthreads();
        }
    }

    // ---- combine logits to LDS ----
#pragma unroll
    for (int nt = 0; nt < 4; ++nt)
#pragma unroll
        for (int r = 0; r < 4; ++r) {
            const int t = w * 16 + g * 4 + r;
            ls[t * 68 + nt * 16 + c15] = acc2h[nt][r] + acc2x[nt][r] * (1.f / 4096.f);
        }
    __syncthreads();

    // ---- epilogue (round-2 verified): lane == expert ----
    const int e = lane;
    const float be = b2[e];
#pragma unroll 1
    for (int i = 0; i < 16; ++i) {
        const float l = ls[(w * 16 + i) * 68 + e] + be;

        float v = l; int idx = e;
#pragma unroll
        for (int m = 32; m >= 1; m >>= 1) {
            const float ov = __shfl_xor(v, m, 64);
            const int   oi = __shfl_xor(idx, m, 64);
            if (ov > v || (ov == v && oi < idx)) { v = ov; idx = oi; }
        }
        const float m1 = v; const int i1 = idx;

        v = (e == i1) ? -INFINITY : l; idx = e;
#pragma unroll
        for (int m = 32; m >= 1; m >>= 1) {
            const float ov = __shfl_xor(v, m, 64);
            const int   oi = __shfl_xor(idx, m, 64);
            if (ov > v || (ov == v && oi < idx)) { v = ov; idx = oi; }
        }
        const int i2 = idx;

        const float ex = expf((l - m1) * 100.0f);
        float s = ex;
#pragma unroll
        for (int m = 32; m >= 1; m >>= 1) s += __shfl_xor(s, m, 64);
        const float ori = ex / s;

        const float q = (e == i1 || e == i2) ? expf(l - m1) : 0.f;
        float s2 = q;
#pragma unroll
        for (int m = 32; m >= 1; m >>= 1) s2 += __shfl_xor(s2, m, 64);
        const float rtr = q / s2;

        const size_t tok = tok0 + (size_t)w * 16 + i;
        out[O_ORI + tok * E_EXP + e] = ori;
        out[O_RTR + tok * E_EXP + e] = rtr;
        if (e == 0) {
            out[O_IDX + tok * 2 + 0] = (float)i1;
            out[O_IDX + tok * 2 + 1] = (float)i2;
        }
    }
}

// ============ fallback: round-2 kernel (known-good), used if ws too small ============

#define XPITCH 80
#define WPITCH 80
#define HPITCH 132

__launch_bounds__(256, 2)
__global__ void router_fused_v2(const float* __restrict__ x,
                                const float* __restrict__ W1,
                                const float* __restrict__ bias1,
                                const float* __restrict__ W2,
                                const float* __restrict__ bias2,
                                float* __restrict__ out)
{
    __shared__ __align__(16) unsigned char xs_h[BT * XPITCH];
    __shared__ __align__(16) unsigned char xs_l[BT * XPITCH];
    __shared__ __align__(16) unsigned char w1s_h[128 * WPITCH];
    __shared__ __align__(16) unsigned char w1s_l[128 * WPITCH];
    __shared__ float hsf[BT][HPITCH];

    const int tid  = threadIdx.x;
    const int lane = tid & 63;
    const int wid  = tid >> 6;
    const size_t tok0 = (size_t)blockIdx.x * BT;
    const int wr = wid >> 1, wc = wid & 1;
    const int sx_r = tid >> 2;
    const int sx_d = (tid & 3) * 8;
    const int sw_f = tid & 127;
    const int sw_q = tid >> 7;
    const int e = lane;

    float lacc[16];
#pragma unroll
    for (int i = 0; i < 16; ++i) lacc[i] = 0.f;

    for (int fc = 0; fc < F_HID; fc += 128) {
        f32x4 acc_hh[2][4], acc_x[2][4];
#pragma unroll
        for (int mt = 0; mt < 2; ++mt)
#pragma unroll
            for (int nt = 0; nt < 4; ++nt) {
                acc_hh[mt][nt] = (f32x4){0.f, 0.f, 0.f, 0.f};
                acc_x[mt][nt]  = (f32x4){0.f, 0.f, 0.f, 0.f};
            }
        for (int d0 = 0; d0 < D_IN; d0 += 32) {
            __syncthreads();
            {
                const float* xp = &x[(tok0 + sx_r) * D_IN + d0 + sx_d];
                const float4 v0 = *(const float4*)xp;
                const float4 v1 = *(const float4*)(xp + 4);
                const float vv[8] = {v0.x, v0.y, v0.z, v0.w, v1.x, v1.y, v1.z, v1.w};
                half8 hh, hl;
#pragma unroll
                for (int j = 0; j < 8; ++j) {
                    const float v = vv[j];
                    const _Float16 h = (_Float16)v;
                    const float r = v - (float)h;
                    hh[j] = h; hl[j] = (_Float16)(r * 4096.f);
                }
                *(half8*)(xs_h + sx_r * XPITCH + sx_d * 2) = hh;
                *(half8*)(xs_l + sx_r * XPITCH + sx_d * 2) = hl;
            }
            {
                const float* wp = &W1[(size_t)(d0 + sw_q * 16) * F_HID + fc + sw_f];
                half8 h0, h1, l0, l1;
#pragma unroll
                for (int j = 0; j < 8; ++j) {
                    const float v = wp[(size_t)j * F_HID];
                    const _Float16 h = (_Float16)v;
                    const float r = v - (float)h;
                    h0[j] = h; l0[j] = (_Float16)(r * 4096.f);
                }
#pragma unroll
                for (int j = 0; j < 8; ++j) {
                    const float v = wp[(size_t)(j + 8) * F_HID];
                    const _Float16 h = (_Float16)v;
                    const float r = v - (float)h;
                    h1[j] = h; l1[j] = (_Float16)(r * 4096.f);
                }
                unsigned char* bh_ = w1s_h + sw_f * WPITCH + sw_q * 32;
                unsigned char* bl_ = w1s_l + sw_f * WPITCH + sw_q * 32;
                *(half8*)(bh_)      = h0;
                *(half8*)(bh_ + 16) = h1;
                *(half8*)(bl_)      = l0;
                *(half8*)(bl_ + 16) = l1;
            }
            __syncthreads();
            const int koff = (lane >> 4) * 16;
            half8 ah[2], al[2], bh[4], bl[4];
#pragma unroll
            for (int mt = 0; mt < 2; ++mt) {
                const int row = wr * 32 + mt * 16 + (lane & 15);
                ah[mt] = *(const half8*)(xs_h + row * XPITCH + koff);
                al[mt] = *(const half8*)(xs_l + row * XPITCH + koff);
            }
#pragma unroll
            for (int nt = 0; nt < 4; ++nt) {
                const int f = wc * 64 + nt * 16 + (lane & 15);
                bh[nt] = *(const half8*)(w1s_h + f * WPITCH + koff);
                bl[nt] = *(const half8*)(w1s_l + f * WPITCH + koff);
            }
#pragma unroll
            for (int mt = 0; mt < 2; ++mt)
#pragma unroll
                for (int nt = 0; nt < 4; ++nt) {
                    acc_hh[mt][nt] = __builtin_amdgcn_mfma_f32_16x16x32_f16(ah[mt], bh[nt], acc_hh[mt][nt], 0, 0, 0);
                    acc_x[mt][nt]  = __builtin_amdgcn_mfma_f32_16x16x32_f16(ah[mt], bl[nt], acc_x[mt][nt], 0, 0, 0);
                    acc_x[mt][nt]  = __builtin_amdgcn_mfma_f32_16x16x32_f16(al[mt], bh[nt], acc_x[mt][nt], 0, 0, 0);
                }
        }
#pragma unroll
        for (int mt = 0; mt < 2; ++mt)
#pragma unroll
            for (int nt = 0; nt < 4; ++nt) {
                const int f = wc * 64 + nt * 16 + (lane & 15);
                const float bv = bias1[fc + f];
#pragma unroll
                for (int r = 0; r < 4; ++r) {
                    const int row = wr * 32 + mt * 16 + (lane >> 4) * 4 + r;
                    const float v = acc_hh[mt][nt][r] + acc_x[mt][nt][r] * (1.f / 4096.f) + bv;
                    hsf[row][f] = fmaxf(v, 0.f);
                }
            }
        __syncthreads();
        for (int f = 0; f < 128; f += 4) {
            const float w0  = W2[(size_t)(fc + f + 0) * E_EXP + e];
            const float w1v = W2[(size_t)(fc + f + 1) * E_EXP + e];
            const float w2v = W2[(size_t)(fc + f + 2) * E_EXP + e];
            const float w3v = W2[(size_t)(fc + f + 3) * E_EXP + e];
#pragma unroll
            for (int i = 0; i < 16; ++i) {
                const float4 hv = *(const float4*)&hsf[wid * 16 + i][f];
                lacc[i] = fmaf(hv.x, w0,  lacc[i]);
                lacc[i] = fmaf(hv.y, w1v, lacc[i]);
                lacc[i] = fmaf(hv.z, w2v, lacc[i]);
                lacc[i] = fmaf(hv.w, w3v, lacc[i]);
            }
        }
    }

    const float be = bias2[e];
#pragma unroll 1
    for (int i = 0; i < 16; ++i) {
        const float l = lacc[i] + be;
        float v = l; int idx = e;
#pragma unroll
        for (int m = 32; m >= 1; m >>= 1) {
            const float ov = __shfl_xor(v, m, 64);
            const int   oi = __shfl_xor(idx, m, 64);
            if (ov > v || (ov == v && oi < idx)) { v = ov; idx = oi; }
        }
        const float m1 = v; const int i1 = idx;
        v = (e == i1) ? -INFINITY : l; idx = e;
#pragma unroll
        for (int m = 32; m >= 1; m >>= 1) {
            const float ov = __shfl_xor(v, m, 64);
            const int   oi = __shfl_xor(idx, m, 64);
            if (ov > v || (ov == v && oi < idx)) { v = ov; idx = oi; }
        }
        const int i2 = idx;
        const float ex = expf((l - m1) * 100.0f);
        float s = ex;
#pragma unroll
        for (int m = 32; m >= 1; m >>= 1) s += __shfl_xor(s, m, 64);
        const float ori = ex / s;
        const float q = (e == i1 || e == i2) ? expf(l - m1) : 0.f;
        float s2 = q;
#pragma unroll
        for (int m = 32; m >= 1; m >>= 1) s2 += __shfl_xor(s2, m, 64);
        const float rtr = q / s2;
        const size_t tok = tok0 + (size_t)wid * 16 + i;
        out[O_ORI + tok * E_EXP + e] = ori;
        out[O_RTR + tok * E_EXP + e] = rtr;
        if (e == 0) {
            out[O_IDX + tok * 2 + 0] = (float)i1;
            out[O_IDX + tok * 2 + 1] = (float)i2;
        }
    }
}

// ============ launcher ============

extern "C" void kernel_launch(void* const* d_in, const int* in_sizes, int n_in,
                              void* d_out, int out_size, void* d_ws, size_t ws_size,
                              hipStream_t stream) {
    const float* x  = (const float*)d_in[0];
    const float* W1 = (const float*)d_in[1];
    const float* b1 = (const float*)d_in[2];
    const float* W2 = (const float*)d_in[3];
    const float* b2 = (const float*)d_in[4];
    float* out = (float*)d_out;

    if (ws_size >= WS_NEED) {
        unsigned char* ws = (unsigned char*)d_ws;
        unsigned short* xh  = (unsigned short*)(ws + WS_XH);
        unsigned short* xl  = (unsigned short*)(ws + WS_XL);
        unsigned short* w1h = (unsigned short*)(ws + WS_W1H);
        unsigned short* w1l = (unsigned short*)(ws + WS_W1L);
        unsigned short* w2h = (unsigned short*)(ws + WS_W2H);
        unsigned short* w2l = (unsigned short*)(ws + WS_W2L);

        hipLaunchKernelGGL(split_x_k,  dim3(M_TOK * D_IN / 4 / 256), dim3(256), 0, stream, x, xh, xl);
        hipLaunchKernelGGL(split_w1t_k, dim3(D_IN / 32, F_HID / 32), dim3(256), 0, stream, W1, w1h, w1l);
        hipLaunchKernelGGL(split_w2t_k, dim3(F_HID * E_EXP / 4 / 256), dim3(256), 0, stream, W2, w2h, w2l);
        hipLaunchKernelGGL(router_mfma, dim3(M_TOK / BT), dim3(256), 0, stream,
                           xh, xl, w1h, w1l, w2h, w2l, b1, b2, out);
    } else {
        hipLaunchKernelGGL(router_fused_v2, dim3(M_TOK / BT / 1), dim3(256), 0, stream,
                           x, W1, b1, W2, b2, out);
    }
}

// Round 4
// 582.557 us; speedup vs baseline: 3.6763x; 1.0472x over previous
//
#include <hip/hip_runtime.h>
#include <math.h>
#include <stdint.h>

// Problem constants
#define M_TOK 32768   // B*S
#define D_IN  1024
#define F_HID 2048
#define E_EXP 64

#define O_ORI 0
#define O_RTR (M_TOK * E_EXP)
#define O_IDX (2 * M_TOK * E_EXP)

typedef _Float16 half8 __attribute__((ext_vector_type(8)));
typedef float    f32x4 __attribute__((ext_vector_type(4)));
typedef unsigned int uint32;
typedef uint32   u32x4 __attribute__((ext_vector_type(4)));

// ---- workspace layout (bytes) ----
#define WS_XH  ((size_t)0)
#define WS_XL  (WS_XH  + (size_t)M_TOK * D_IN * 2)
#define WS_W1H (WS_XL  + (size_t)M_TOK * D_IN * 2)
#define WS_W1L (WS_W1H + (size_t)D_IN * F_HID * 2)
#define WS_W2H (WS_W1L + (size_t)D_IN * F_HID * 2)
#define WS_W2L (WS_W2H + (size_t)F_HID * E_EXP * 2)
#define WS_H   (WS_W2L + (size_t)F_HID * E_EXP * 2)
#define WS_NEED_SPLIT (WS_H)                               // fused fallback path
#define WS_NEED_FULL  (WS_H + (size_t)M_TOK * F_HID * 4)   // + h buffer (256MB)

// Split with baked scale: plane1 = sc*hi(v) (exact), plane2 = sc*(v - hi(v))
__device__ __forceinline__ void split_sc(float v, float sc, unsigned short& h, unsigned short& l) {
    const _Float16 hh = (_Float16)v;
    const float hf = (float)hh;
    const _Float16 hs = (_Float16)(hf * sc);          // exact (power-of-2 scale)
    const _Float16 ls = (_Float16)((v - hf) * sc);
    h = __builtin_bit_cast(unsigned short, hs);
    l = __builtin_bit_cast(unsigned short, ls);
}

// ============ prep kernels ============
// x, W1 planes: scale 64  (products => 4096 * true value, single accumulator)
// W2 planes:    scale 16  (h planes also 16 => 256 * logit)

__global__ void split_x_k(const float* __restrict__ x,
                          unsigned short* __restrict__ xh, unsigned short* __restrict__ xl) {
    size_t i = ((size_t)blockIdx.x * 256 + threadIdx.x) * 4;
    const float4 v = *(const float4*)&x[i];
    ushort4 h, l;
    split_sc(v.x, 64.f, h.x, l.x); split_sc(v.y, 64.f, h.y, l.y);
    split_sc(v.z, 64.f, h.z, l.z); split_sc(v.w, 64.f, h.w, l.w);
    *(ushort4*)&xh[i] = h;
    *(ushort4*)&xl[i] = l;
}

__global__ void split_w1t_k(const float* __restrict__ W1,
                            unsigned short* __restrict__ wh, unsigned short* __restrict__ wl) {
    __shared__ float t[32][33];
    const int d0 = blockIdx.x * 32;
    const int f0 = blockIdx.y * 32;
    const int r  = threadIdx.x >> 3;
    const int c4 = (threadIdx.x & 7) * 4;
    const float4 v = *(const float4*)&W1[(size_t)(d0 + r) * F_HID + f0 + c4];
    t[r][c4 + 0] = v.x; t[r][c4 + 1] = v.y; t[r][c4 + 2] = v.z; t[r][c4 + 3] = v.w;
    __syncthreads();
    ushort4 h, l;
    split_sc(t[c4 + 0][r], 64.f, h.x, l.x);
    split_sc(t[c4 + 1][r], 64.f, h.y, l.y);
    split_sc(t[c4 + 2][r], 64.f, h.z, l.z);
    split_sc(t[c4 + 3][r], 64.f, h.w, l.w);
    *(ushort4*)&wh[(size_t)(f0 + r) * D_IN + d0 + c4] = h;
    *(ushort4*)&wl[(size_t)(f0 + r) * D_IN + d0 + c4] = l;
}

__global__ void split_w2t_k(const float* __restrict__ W2,
                            unsigned short* __restrict__ wh, unsigned short* __restrict__ wl) {
    const int gid = blockIdx.x * 256 + threadIdx.x;
    const int e  = gid >> 9;
    const int f4 = (gid & 511) * 4;
    ushort4 h, l;
    split_sc(W2[(size_t)(f4 + 0) * E_EXP + e], 16.f, h.x, l.x);
    split_sc(W2[(size_t)(f4 + 1) * E_EXP + e], 16.f, h.y, l.y);
    split_sc(W2[(size_t)(f4 + 2) * E_EXP + e], 16.f, h.z, l.z);
    split_sc(W2[(size_t)(f4 + 3) * E_EXP + e], 16.f, h.w, l.w);
    *(ushort4*)&wh[(size_t)e * F_HID + f4] = h;
    *(ushort4*)&wl[(size_t)e * F_HID + f4] = l;
}

// ============ common helpers ============

__device__ __forceinline__ uint32 swz(uint32 o) { return o ^ (((o >> 7) & 7u) << 4); }

#define STAGE16(SRCP, DSTP) \
    __builtin_amdgcn_global_load_lds((const __attribute__((address_space(1))) void*)(SRCP), \
                                     (__attribute__((address_space(3))) void*)(DSTP), 16, 0, 0)

// ============ kernel A: GEMM1 (256x256 tile, BK=32, 8 waves, counted-vmcnt pipeline) ============

__launch_bounds__(512, 2)
__global__ void gemm1_8w(const unsigned short* __restrict__ xh, const unsigned short* __restrict__ xl,
                         const unsigned short* __restrict__ w1h, const unsigned short* __restrict__ w1l,
                         const float* __restrict__ b1,
                         uint32* __restrict__ hout)
{
    // 2 x (hi-plane 16K + lo-plane 16K) for A and B = 128 KiB
    __shared__ __align__(16) unsigned char As[2][32768];
    __shared__ __align__(16) unsigned char Bs[2][32768];

    const int tid  = threadIdx.x;
    const int lane = tid & 63;
    const int w    = tid >> 6;         // 0..7
    const int c15  = lane & 15;
    const int g    = lane >> 4;
    const int wr   = w >> 2;           // 0..1 : 128-token half
    const int wc   = w & 3;            // 0..3 : 64-f quarter

    const int bid  = blockIdx.x;       // 1024 = 128 m-blocks x 8 f-blocks
    const int fblk = bid & 7;          // same f -> same XCD (round-robin dispatch)
    const int mblk = bid >> 3;
    const size_t tok0 = (size_t)mblk * 256;
    const int f0 = fblk * 256;

    // staging lane->source mapping (2 chunks per plane per thread; both-sides swizzle)
    uint32 srow[2], shalf[2];
#pragma unroll
    for (int j = 0; j < 2; ++j) {
        const uint32 c_ = (uint32)(w + 8 * j);
        const uint32 s_ = swz(c_ * 1024u + (uint32)lane * 16u);
        srow[j] = s_ >> 6; shalf[j] = (s_ & 63u) >> 1;
    }

    // fragment read offsets (loop-invariant, swizzled)
    uint32 offA[8], offB[4];
#pragma unroll
    for (int m = 0; m < 8; ++m)
        offA[m] = swz((uint32)(wr * 128 + m * 16 + c15) * 64u + (uint32)g * 16u);
#pragma unroll
    for (int n = 0; n < 4; ++n)
        offB[n] = swz((uint32)(wc * 64 + n * 16 + c15) * 64u + (uint32)g * 16u);

    f32x4 acc[8][4];
#pragma unroll
    for (int m = 0; m < 8; ++m)
#pragma unroll
        for (int n = 0; n < 4; ++n) acc[m][n] = (f32x4){0.f, 0.f, 0.f, 0.f};

#define STAGE_T(T, BUF) do {                                                        \
    const int d0_ = (T) * 32;                                                       \
    _Pragma("unroll")                                                               \
    for (int j = 0; j < 2; ++j) {                                                   \
        const uint32 c_ = (uint32)(w + 8 * j);                                      \
        const size_t asrc = (tok0 + srow[j]) * D_IN + (size_t)(d0_ + (int)shalf[j]);\
        const size_t bsrc = ((size_t)(f0) + srow[j]) * D_IN + (size_t)(d0_ + (int)shalf[j]); \
        STAGE16(xh  + asrc, &As[BUF][c_ * 1024]);                                   \
        STAGE16(xl  + asrc, &As[BUF][16384 + c_ * 1024]);                           \
        STAGE16(w1h + bsrc, &Bs[BUF][c_ * 1024]);                                   \
        STAGE16(w1l + bsrc, &Bs[BUF][16384 + c_ * 1024]);                           \
    } } while (0)

    STAGE_T(0, 0);
    STAGE_T(1, 1);

#pragma unroll 1
    for (int t = 0; t < 32; ++t) {
        if (t < 31) asm volatile("s_waitcnt vmcnt(8)" ::: "memory");
        else        asm volatile("s_waitcnt vmcnt(0)" ::: "memory");
        __builtin_amdgcn_s_barrier();
        const unsigned char* Ab = As[t & 1];
        const unsigned char* Bb = Bs[t & 1];

        half8 b1f[4], b2f[4];
#pragma unroll
        for (int n = 0; n < 4; ++n) {
            b1f[n] = *(const half8*)(Bb + offB[n]);
            b2f[n] = *(const half8*)(Bb + 16384 + offB[n]);
        }
        half8 a1f[4], a2f[4];
#pragma unroll
        for (int m = 0; m < 4; ++m) {
            a1f[m] = *(const half8*)(Ab + offA[m]);
            a2f[m] = *(const half8*)(Ab + 16384 + offA[m]);
        }
        __builtin_amdgcn_s_setprio(1);
#pragma unroll
        for (int m = 0; m < 4; ++m)
#pragma unroll
            for (int n = 0; n < 4; ++n) {
                acc[m][n] = __builtin_amdgcn_mfma_f32_16x16x32_f16(a1f[m], b1f[n], acc[m][n], 0, 0, 0);
                acc[m][n] = __builtin_amdgcn_mfma_f32_16x16x32_f16(a1f[m], b2f[n], acc[m][n], 0, 0, 0);
                acc[m][n] = __builtin_amdgcn_mfma_f32_16x16x32_f16(a2f[m], b1f[n], acc[m][n], 0, 0, 0);
            }
        __builtin_amdgcn_s_setprio(0);
#pragma unroll
        for (int m = 0; m < 4; ++m) {
            a1f[m] = *(const half8*)(Ab + offA[4 + m]);
            a2f[m] = *(const half8*)(Ab + 16384 + offA[4 + m]);
        }
        __builtin_amdgcn_s_setprio(1);
#pragma unroll
        for (int m = 0; m < 4; ++m)
#pragma unroll
            for (int n = 0; n < 4; ++n) {
                acc[4 + m][n] = __builtin_amdgcn_mfma_f32_16x16x32_f16(a1f[m], b1f[n], acc[4 + m][n], 0, 0, 0);
                acc[4 + m][n] = __builtin_amdgcn_mfma_f32_16x16x32_f16(a1f[m], b2f[n], acc[4 + m][n], 0, 0, 0);
                acc[4 + m][n] = __builtin_amdgcn_mfma_f32_16x16x32_f16(a2f[m], b1f[n], acc[4 + m][n], 0, 0, 0);
            }
        __builtin_amdgcn_s_setprio(0);
        __builtin_amdgcn_s_barrier();
        if (t + 2 < 32) STAGE_T(t + 2, t & 1);
    }
#undef STAGE_T

    // epilogue: h = relu(acc/4096 + b1) -> split-pack u32 {16*hi | 16*res<<16}
    float bv[4];
#pragma unroll
    for (int n = 0; n < 4; ++n) bv[n] = b1[f0 + wc * 64 + n * 16 + c15];
#pragma unroll
    for (int m = 0; m < 8; ++m) {
        const size_t rowbase = (tok0 + (size_t)(wr * 128 + m * 16 + g * 4)) * F_HID;
#pragma unroll
        for (int n = 0; n < 4; ++n) {
            const int fcol = f0 + wc * 64 + n * 16 + c15;
#pragma unroll
            for (int r = 0; r < 4; ++r) {
                float hv = acc[m][n][r] * (1.f / 4096.f) + bv[n];
                hv = fmaxf(hv, 0.f);
                const _Float16 hh = (_Float16)hv;
                const float hf = (float)hh;
                const _Float16 hsv = (_Float16)(hf * 16.f);
                const _Float16 lsv = (_Float16)((hv - hf) * 16.f);
                const uint32 pk = (uint32)__builtin_bit_cast(unsigned short, hsv)
                                | ((uint32)__builtin_bit_cast(unsigned short, lsv) << 16);
                hout[rowbase + (size_t)r * F_HID + fcol] = pk;
            }
        }
    }
}

// ============ kernel B: GEMM2 + top-k + softmaxes (streaming h) ============

__launch_bounds__(256, 2)
__global__ void gemm2_epi(const uint32* __restrict__ hin,
                          const unsigned short* __restrict__ w2h, const unsigned short* __restrict__ w2l,
                          const float* __restrict__ b2,
                          float* __restrict__ out)
{
    __shared__ float ls[128 * 68];
    const int tid  = threadIdx.x;
    const int lane = tid & 63;
    const int w    = tid >> 6;
    const int c15  = lane & 15;
    const int g    = lane >> 4;
    const size_t tok0 = (size_t)blockIdx.x * 128;

    f32x4 acc[2][4];
#pragma unroll
    for (int mt = 0; mt < 2; ++mt)
#pragma unroll
        for (int nt = 0; nt < 4; ++nt) acc[mt][nt] = (f32x4){0.f, 0.f, 0.f, 0.f};

#pragma unroll 1
    for (int it = 0; it < 64; ++it) {
        const int fk = it * 32 + g * 8;
        half8 bf1[4], bf2[4];
#pragma unroll
        for (int nt = 0; nt < 4; ++nt) {
            const size_t eoff = (size_t)(nt * 16 + c15) * F_HID + fk;
            bf1[nt] = *(const half8*)&w2h[eoff];
            bf2[nt] = *(const half8*)&w2l[eoff];
        }
#pragma unroll
        for (int mt = 0; mt < 2; ++mt) {
            const uint32* hp = hin + (tok0 + (size_t)(w * 32 + mt * 16 + c15)) * F_HID + fk;
            const u32x4 q0 = *(const u32x4*)hp;
            const u32x4 q1 = *(const u32x4*)(hp + 4);
            u32x4 hi4, lo4;
            hi4[0] = __builtin_amdgcn_perm(q0[1], q0[0], 0x05040100u);
            hi4[1] = __builtin_amdgcn_perm(q0[3], q0[2], 0x05040100u);
            hi4[2] = __builtin_amdgcn_perm(q1[1], q1[0], 0x05040100u);
            hi4[3] = __builtin_amdgcn_perm(q1[3], q1[2], 0x05040100u);
            lo4[0] = __builtin_amdgcn_perm(q0[1], q0[0], 0x07060302u);
            lo4[1] = __builtin_amdgcn_perm(q0[3], q0[2], 0x07060302u);
            lo4[2] = __builtin_amdgcn_perm(q1[1], q1[0], 0x07060302u);
            lo4[3] = __builtin_amdgcn_perm(q1[3], q1[2], 0x07060302u);
            const half8 a1 = __builtin_bit_cast(half8, hi4);
            const half8 a2 = __builtin_bit_cast(half8, lo4);
#pragma unroll
            for (int nt = 0; nt < 4; ++nt) {
                acc[mt][nt] = __builtin_amdgcn_mfma_f32_16x16x32_f16(a1, bf1[nt], acc[mt][nt], 0, 0, 0);
                acc[mt][nt] = __builtin_amdgcn_mfma_f32_16x16x32_f16(a1, bf2[nt], acc[mt][nt], 0, 0, 0);
                acc[mt][nt] = __builtin_amdgcn_mfma_f32_16x16x32_f16(a2, bf1[nt], acc[mt][nt], 0, 0, 0);
            }
        }
    }

    // combine (acc = 256 * logit) -> ls
#pragma unroll
    for (int mt = 0; mt < 2; ++mt)
#pragma unroll
        for (int nt = 0; nt < 4; ++nt)
#pragma unroll
            for (int r = 0; r < 4; ++r)
                ls[(w * 32 + mt * 16 + g * 4 + r) * 68 + nt * 16 + c15] = acc[mt][nt][r] * (1.f / 256.f);
    __syncthreads();

    // epilogue: lane == expert, 32 rows per wave
    const int e = lane;
    const float be = b2[e];
#pragma unroll 1
    for (int i = 0; i < 32; ++i) {
        const float l = ls[(w * 32 + i) * 68 + e] + be;

        float v = l; int idx = e;
#pragma unroll
        for (int m = 32; m >= 1; m >>= 1) {
            const float ov = __shfl_xor(v, m, 64);
            const int   oi = __shfl_xor(idx, m, 64);
            if (ov > v || (ov == v && oi < idx)) { v = ov; idx = oi; }
        }
        const float m1 = v; const int i1 = idx;

        v = (e == i1) ? -INFINITY : l; idx = e;
#pragma unroll
        for (int m = 32; m >= 1; m >>= 1) {
            const float ov = __shfl_xor(v, m, 64);
            const int   oi = __shfl_xor(idx, m, 64);
            if (ov > v || (ov == v && oi < idx)) { v = ov; idx = oi; }
        }
        const int i2 = idx;

        const float ex = expf((l - m1) * 100.0f);
        float s = ex;
#pragma unroll
        for (int m = 32; m >= 1; m >>= 1) s += __shfl_xor(s, m, 64);
        const float ori = ex / s;

        const float q = (e == i1 || e == i2) ? expf(l - m1) : 0.f;
        float s2 = q;
#pragma unroll
        for (int m = 32; m >= 1; m >>= 1) s2 += __shfl_xor(s2, m, 64);
        const float rtr = q / s2;

        const size_t tok = tok0 + (size_t)w * 32 + i;
        out[O_ORI + tok * E_EXP + e] = ori;
        out[O_RTR + tok * E_EXP + e] = rtr;
        if (e == 0) {
            out[O_IDX + tok * 2 + 0] = (float)i1;
            out[O_IDX + tok * 2 + 1] = (float)i2;
        }
    }
}

// ============ fallback: round-3 fused kernel, adjusted for new plane scales ============

#define BT  64
#define NB  256

__launch_bounds__(256, 2)
__global__ void router_mfma(const unsigned short* __restrict__ xh, const unsigned short* __restrict__ xl,
                            const unsigned short* __restrict__ w1h, const unsigned short* __restrict__ w1l,
                            const unsigned short* __restrict__ w2h, const unsigned short* __restrict__ w2l,
                            const float* __restrict__ b1, const float* __restrict__ b2,
                            float* __restrict__ out)
{
    __shared__ __align__(16) unsigned char xs_h[BT * 64];
    __shared__ __align__(16) unsigned char xs_l[BT * 64];
    __shared__ __align__(16) unsigned char w1s_h[NB * 64];
    __shared__ __align__(16) unsigned char w1s_l[NB * 64];
    __shared__ __align__(16) unsigned char hsbuf[BT * 132 * 4];

    const int tid  = threadIdx.x;
    const int lane = tid & 63;
    const int w    = tid >> 6;
    const int c15  = lane & 15;
    const int g    = lane >> 4;
    const size_t tok0 = (size_t)blockIdx.x * BT;

    uint32* hs = (uint32*)hsbuf;
    float*  ls = (float*)hsbuf;

    f32x4 acc2h[4], acc2x[4];
#pragma unroll
    for (int nt = 0; nt < 4; ++nt) {
        acc2h[nt] = (f32x4){0.f, 0.f, 0.f, 0.f};
        acc2x[nt] = (f32x4){0.f, 0.f, 0.f, 0.f};
    }

    const uint32 kqb = (uint32)g * 16u;

    for (int fc = 0; fc < F_HID; fc += NB) {
        f32x4 ahh[4][4], axx[4][4];
#pragma unroll
        for (int mt = 0; mt < 4; ++mt)
#pragma unroll
            for (int nt = 0; nt < 4; ++nt) {
                ahh[mt][nt] = (f32x4){0.f, 0.f, 0.f, 0.f};
                axx[mt][nt] = (f32x4){0.f, 0.f, 0.f, 0.f};
            }

        for (int d0 = 0; d0 < D_IN; d0 += 32) {
            __syncthreads();
            {
                uint32 o = (uint32)w * 1024u + (uint32)lane * 16u;
                uint32 s = swz(o);
                uint32 r = s >> 6, hb = (s & 63u) >> 1;
                const unsigned short* sp;
                sp = xh + (tok0 + r) * D_IN + (size_t)(d0 + (int)hb);
                STAGE16(sp, xs_h + (size_t)w * 1024);
                sp = xl + (tok0 + r) * D_IN + (size_t)(d0 + (int)hb);
                STAGE16(sp, xs_l + (size_t)w * 1024);
#pragma unroll
                for (int q = 0; q < 4; ++q) {
                    const uint32 c_ = (uint32)(q * 4 + w);
                    uint32 o2 = c_ * 1024u + (uint32)lane * 16u;
                    uint32 s2 = swz(o2);
                    uint32 r2 = s2 >> 6, hb2 = (s2 & 63u) >> 1;
                    sp = w1h + ((size_t)(fc + (int)r2)) * D_IN + (size_t)(d0 + (int)hb2);
                    STAGE16(sp, w1s_h + (size_t)c_ * 1024);
                    sp = w1l + ((size_t)(fc + (int)r2)) * D_IN + (size_t)(d0 + (int)hb2);
                    STAGE16(sp, w1s_l + (size_t)c_ * 1024);
                }
            }
            __syncthreads();

            half8 ah[4], al[4], bh[4], bl[4];
#pragma unroll
            for (int mt = 0; mt < 4; ++mt) {
                const uint32 off = swz((uint32)(mt * 16 + c15) * 64u + kqb);
                ah[mt] = *(const half8*)(xs_h + off);
                al[mt] = *(const half8*)(xs_l + off);
            }
#pragma unroll
            for (int nt = 0; nt < 4; ++nt) {
                const uint32 row = (uint32)(w * 64 + nt * 16 + c15);
                const uint32 off = swz(row * 64u + kqb);
                bh[nt] = *(const half8*)(w1s_h + off);
                bl[nt] = *(const half8*)(w1s_l + off);
            }
#pragma unroll
            for (int mt = 0; mt < 4; ++mt)
#pragma unroll
                for (int nt = 0; nt < 4; ++nt) {
                    ahh[mt][nt] = __builtin_amdgcn_mfma_f32_16x16x32_f16(ah[mt], bh[nt], ahh[mt][nt], 0, 0, 0);
                    axx[mt][nt] = __builtin_amdgcn_mfma_f32_16x16x32_f16(ah[mt], bl[nt], axx[mt][nt], 0, 0, 0);
                    axx[mt][nt] = __builtin_amdgcn_mfma_f32_16x16x32_f16(al[mt], bh[nt], axx[mt][nt], 0, 0, 0);
                }
        }

        const int fl0 = (w & 1) * 64;
#pragma unroll
        for (int phase = 0; phase < 2; ++phase) {
            if ((w >> 1) == phase) {
#pragma unroll
                for (int nt = 0; nt < 4; ++nt) {
                    const float b1v = b1[fc + w * 64 + nt * 16 + c15];
#pragma unroll
                    for (int mt = 0; mt < 4; ++mt) {
#pragma unroll
                        for (int r = 0; r < 4; ++r) {
                            float hv = (ahh[mt][nt][r] + axx[mt][nt][r]) * (1.f / 4096.f) + b1v;
                            hv = fmaxf(hv, 0.f);
                            const _Float16 hhv0 = (_Float16)hv;
                            const float hf = (float)hhv0;
                            const _Float16 hhv = (_Float16)(hf * 16.f);
                            const _Float16 hlv = (_Float16)((hv - hf) * 16.f);
                            uint32 pk = (uint32)__builtin_bit_cast(unsigned short, hhv)
                                      | ((uint32)__builtin_bit_cast(unsigned short, hlv) << 16);
                            const int t = mt * 16 + g * 4 + r;
                            hs[t * 132 + fl0 + nt * 16 + c15] = pk;
                        }
                    }
                }
            }
            __syncthreads();
            const int tA = w * 16 + c15;
#pragma unroll
            for (int ktl = 0; ktl < 4; ++ktl) {
                const u32x4 q0 = *(const u32x4*)&hs[tA * 132 + ktl * 32 + g * 8];
                const u32x4 q1 = *(const u32x4*)&hs[tA * 132 + ktl * 32 + g * 8 + 4];
                u32x4 hi4, lo4;
                hi4[0] = __builtin_amdgcn_perm(q0[1], q0[0], 0x05040100u);
                hi4[1] = __builtin_amdgcn_perm(q0[3], q0[2], 0x05040100u);
                hi4[2] = __builtin_amdgcn_perm(q1[1], q1[0], 0x05040100u);
                hi4[3] = __builtin_amdgcn_perm(q1[3], q1[2], 0x05040100u);
                lo4[0] = __builtin_amdgcn_perm(q0[1], q0[0], 0x07060302u);
                lo4[1] = __builtin_amdgcn_perm(q0[3], q0[2], 0x07060302u);
                lo4[2] = __builtin_amdgcn_perm(q1[1], q1[0], 0x07060302u);
                lo4[3] = __builtin_amdgcn_perm(q1[3], q1[2], 0x07060302u);
                const half8 a_h = __builtin_bit_cast(half8, hi4);
                const half8 a_l = __builtin_bit_cast(half8, lo4);
                const int fG = fc + (phase * 4 + ktl) * 32 + g * 8;
#pragma unroll
                for (int nt = 0; nt < 4; ++nt) {
                    const int e_ = nt * 16 + c15;
                    const half8 b_h = *(const half8*)&w2h[(size_t)e_ * F_HID + fG];
                    const half8 b_l = *(const half8*)&w2l[(size_t)e_ * F_HID + fG];
                    acc2h[nt] = __builtin_amdgcn_mfma_f32_16x16x32_f16(a_h, b_h, acc2h[nt], 0, 0, 0);
                    acc2x[nt] = __builtin_amdgcn_mfma_f32_16x16x32_f16(a_h, b_l, acc2x[nt], 0, 0, 0);
                    acc2x[nt] = __builtin_amdgcn_mfma_f32_16x16x32_f16(a_l, b_h, acc2x[nt], 0, 0, 0);
                }
            }
            __syncthreads();
        }
    }

#pragma unroll
    for (int nt = 0; nt < 4; ++nt)
#pragma unroll
        for (int r = 0; r < 4; ++r) {
            const int t = w * 16 + g * 4 + r;
            ls[t * 68 + nt * 16 + c15] = (acc2h[nt][r] + acc2x[nt][r]) * (1.f / 256.f);
        }
    __syncthreads();

    const int e = lane;
    const float be = b2[e];
#pragma unroll 1
    for (int i = 0; i < 16; ++i) {
        const float l = ls[(w * 16 + i) * 68 + e] + be;

        float v = l; int idx = e;
#pragma unroll
        for (int m = 32; m >= 1; m >>= 1) {
            const float ov = __shfl_xor(v, m, 64);
            const int   oi = __shfl_xor(idx, m, 64);
            if (ov > v || (ov == v && oi < idx)) { v = ov; idx = oi; }
        }
        const float m1 = v; const int i1 = idx;

        v = (e == i1) ? -INFINITY : l; idx = e;
#pragma unroll
        for (int m = 32; m >= 1; m >>= 1) {
            const float ov = __shfl_xor(v, m, 64);
            const int   oi = __shfl_xor(idx, m, 64);
            if (ov > v || (ov == v && oi < idx)) { v = ov; idx = oi; }
        }
        const int i2 = idx;

        const float ex = expf((l - m1) * 100.0f);
        float s = ex;
#pragma unroll
        for (int m = 32; m >= 1; m >>= 1) s += __shfl_xor(s, m, 64);
        const float ori = ex / s;

        const float q = (e == i1 || e == i2) ? expf(l - m1) : 0.f;
        float s2 = q;
#pragma unroll
        for (int m = 32; m >= 1; m >>= 1) s2 += __shfl_xor(s2, m, 64);
        const float rtr = q / s2;

        const size_t tok = tok0 + (size_t)w * 16 + i;
        out[O_ORI + tok * E_EXP + e] = ori;
        out[O_RTR + tok * E_EXP + e] = rtr;
        if (e == 0) {
            out[O_IDX + tok * 2 + 0] = (float)i1;
            out[O_IDX + tok * 2 + 1] = (float)i2;
        }
    }
}

// ============ launcher ============

extern "C" void kernel_launch(void* const* d_in, const int* in_sizes, int n_in,
                              void* d_out, int out_size, void* d_ws, size_t ws_size,
                              hipStream_t stream) {
    const float* x  = (const float*)d_in[0];
    const float* W1 = (const float*)d_in[1];
    const float* b1 = (const float*)d_in[2];
    const float* W2 = (const float*)d_in[3];
    const float* b2 = (const float*)d_in[4];
    float* out = (float*)d_out;

    unsigned char* ws = (unsigned char*)d_ws;
    unsigned short* xh  = (unsigned short*)(ws + WS_XH);
    unsigned short* xl  = (unsigned short*)(ws + WS_XL);
    unsigned short* w1h = (unsigned short*)(ws + WS_W1H);
    unsigned short* w1l = (unsigned short*)(ws + WS_W1L);
    unsigned short* w2h = (unsigned short*)(ws + WS_W2H);
    unsigned short* w2l = (unsigned short*)(ws + WS_W2L);
    uint32*         hbuf = (uint32*)(ws + WS_H);

    if (ws_size >= WS_NEED_FULL) {
        hipLaunchKernelGGL(split_x_k,  dim3(M_TOK * D_IN / 4 / 256), dim3(256), 0, stream, x, xh, xl);
        hipLaunchKernelGGL(split_w1t_k, dim3(D_IN / 32, F_HID / 32), dim3(256), 0, stream, W1, w1h, w1l);
        hipLaunchKernelGGL(split_w2t_k, dim3(F_HID * E_EXP / 4 / 256), dim3(256), 0, stream, W2, w2h, w2l);
        hipLaunchKernelGGL(gemm1_8w, dim3(1024), dim3(512), 0, stream, xh, xl, w1h, w1l, b1, hbuf);
        hipLaunchKernelGGL(gemm2_epi, dim3(M_TOK / 128), dim3(256), 0, stream, hbuf, w2h, w2l, b2, out);
    } else {
        hipLaunchKernelGGL(split_x_k,  dim3(M_TOK * D_IN / 4 / 256), dim3(256), 0, stream, x, xh, xl);
        hipLaunchKernelGGL(split_w1t_k, dim3(D_IN / 32, F_HID / 32), dim3(256), 0, stream, W1, w1h, w1l);
        hipLaunchKernelGGL(split_w2t_k, dim3(F_HID * E_EXP / 4 / 256), dim3(256), 0, stream, W2, w2h, w2l);
        hipLaunchKernelGGL(router_mfma, dim3(M_TOK / BT), dim3(256), 0, stream,
                           xh, xl, w1h, w1l, w2h, w2l, b1, b2, out);
    }
}